// Round 1
// baseline (53.735 us; speedup 1.0000x reference)
//
#include <hip/hip_runtime.h>
#include <hip/hip_bf16.h>
#include <stdint.h>

// Problem: B=8192, I=512, O=512.  out[b,o] = sum_{i,p} x[b,i]^{p+1} * (edge_w[i,o,p]*comb_w[i,o]) + bias[o]
// => GEMM: A[8192,1536] (bf16, kappa = p*512+i) @ W[1536,512] (bf16) + bias, fp32 accum.

static constexpr int MB   = 8192;   // batch rows (M)
static constexpr int IN_  = 512;    // I
static constexpr int ON_  = 512;    // O (N)
static constexpr int KK   = 1536;   // K = 3*I
static constexpr int NKS  = KK / 32; // 48 k-steps of 32

typedef __bf16 bf16x8 __attribute__((ext_vector_type(8)));
typedef float  f32x4  __attribute__((ext_vector_type(4)));

__device__ __forceinline__ unsigned int f2bf(float f) {
    unsigned int u = __float_as_uint(f);
    return ((u + 0x7FFFu + ((u >> 16) & 1u)) >> 16);   // RNE bf16, finite inputs
}

__device__ __forceinline__ void gld_lds16(const void* g, void* l) {
    __builtin_amdgcn_global_load_lds(
        (const __attribute__((address_space(1))) unsigned int*)(uintptr_t)g,
        (__attribute__((address_space(3))) unsigned int*)(unsigned int)(uintptr_t)l,
        16, 0, 0);
}

// ---- pack A: A_packed[rb][ks][lane][8 bf16]; lane l holds A[rb*16+(l&15)][ks*32+(l>>4)*8 + j]
// A[b, kappa] = x[b, kappa%512] ^ (kappa/512 + 1)
__global__ __launch_bounds__(256) void pack_A(const float* __restrict__ x, uint4* __restrict__ Apk) {
    int id   = blockIdx.x * 256 + threadIdx.x;      // ((rb*NKS)+ks)*64 + l
    int l    = id & 63;
    int rbks = id >> 6;
    int ks   = rbks % NKS;
    int rb   = rbks / NKS;
    int b    = rb * 16 + (l & 15);
    int k0   = ks * 32 + ((l >> 4) << 3);
    int p    = k0 >> 9;       // uniform per wave (32 | 512)
    int i0   = k0 & 511;
    const float4* xp = (const float4*)(x + (size_t)b * IN_ + i0);
    float4 v0 = xp[0], v1 = xp[1];
    float f[8] = {v0.x, v0.y, v0.z, v0.w, v1.x, v1.y, v1.z, v1.w};
    unsigned int w[4];
#pragma unroll
    for (int j = 0; j < 4; ++j) {
        float a = f[2 * j], c = f[2 * j + 1];
        float ra = a, rc = c;
        if (p >= 1) { ra *= a; rc *= c; }
        if (p >= 2) { ra *= a; rc *= c; }
        w[j] = f2bf(ra) | (f2bf(rc) << 16);
    }
    Apk[id] = make_uint4(w[0], w[1], w[2], w[3]);
}

// ---- pack B: W_packed[cb][ks][lane][8 bf16]; lane l holds W[ks*32+(l>>4)*8+j][cb*16+(l&15)]
// W[kappa, o] = edge_w[i, o, p] * comb_w[i, o],  i = kappa%512, p = kappa/512
__global__ __launch_bounds__(256) void pack_B(const float* __restrict__ edge_w, const float* __restrict__ comb_w,
                                              uint4* __restrict__ Bpk) {
    int id   = blockIdx.x * 256 + threadIdx.x;      // ((cb*NKS)+ks)*64 + l
    int l    = id & 63;
    int cbks = id >> 6;
    int ks   = cbks % NKS;
    int cb   = cbks / NKS;
    int o    = cb * 16 + (l & 15);
    int k0   = ks * 32 + ((l >> 4) << 3);
    int p    = k0 >> 9;
    int i0   = k0 & 511;
    unsigned int w[4];
#pragma unroll
    for (int j = 0; j < 4; ++j) {
        int ia = i0 + 2 * j, ic = ia + 1;
        float va = edge_w[((size_t)ia * ON_ + o) * 3 + p] * comb_w[(size_t)ia * ON_ + o];
        float vc = edge_w[((size_t)ic * ON_ + o) * 3 + p] * comb_w[(size_t)ic * ON_ + o];
        w[j] = f2bf(va) | (f2bf(vc) << 16);
    }
    Bpk[id] = make_uint4(w[0], w[1], w[2], w[3]);
}

// ---- bias[o] = sum_i comb_w[i,o]*edge_b[i,o]; 16 blocks (2 o-chunks x 8 i-chunks), atomics into zeroed ws
__global__ __launch_bounds__(256) void bias_k(const float* __restrict__ comb_w, const float* __restrict__ edge_b,
                                              float* __restrict__ bias) {
    int t  = threadIdx.x;
    int os = blockIdx.x & 1;
    int is = blockIdx.x >> 1;
    int o  = os * 256 + t;
    float s = 0.f;
    int ib = is * 64;
#pragma unroll 8
    for (int i = ib; i < ib + 64; ++i)
        s += comb_w[(size_t)i * ON_ + o] * edge_b[(size_t)i * ON_ + o];
    atomicAdd(bias + o, s);
}

// ---- GEMM: BM=128, BN=64, BK=32; 256 threads = 4 waves (2x2); double-buffered LDS (24 KB)
// A chunk (1024 B) per (16-row-block, k-step); B chunk per (16-col-block, k-step); all contiguous.
__global__ __launch_bounds__(256) void gemm_k(const char* __restrict__ Apk, const char* __restrict__ Bpk,
                                              const float* __restrict__ bias, float* __restrict__ out) {
    __shared__ char lds[2][12288];   // per buf: A 8 chunks @0, B 4 chunks @8192
    int tid = threadIdx.x;
    int l   = tid & 63;
    int wid = tid >> 6;
    int wr  = wid >> 1, wc = wid & 1;
    int rb0 = blockIdx.x * 8;        // 8 row-blocks of 16 => BM=128
    int cb0 = blockIdx.y * 4;        // 4 col-blocks of 16 => BN=64

    const char* ga0 = Apk + ((size_t)(rb0 + wid)     * NKS) * 1024 + (l << 4);
    const char* ga1 = Apk + ((size_t)(rb0 + 4 + wid) * NKS) * 1024 + (l << 4);
    const char* gb0 = Bpk + ((size_t)(cb0 + wid)     * NKS) * 1024 + (l << 4);

    f32x4 acc[4][2] = {};

    {   // prologue: stage ks=0 into buf 0
        char* buf = lds[0];
        gld_lds16(ga0, buf + (wid << 10));
        gld_lds16(ga1, buf + ((4 + wid) << 10));
        gld_lds16(gb0, buf + 8192 + (wid << 10));
    }
    __syncthreads();

    int cur = 0;
    for (int ks = 0; ks < NKS; ++ks) {
        if (ks + 1 < NKS) {          // stage next tile into other buffer (flies under MFMA)
            char* buf = lds[cur ^ 1];
            size_t off = (size_t)(ks + 1) << 10;
            gld_lds16(ga0 + off, buf + (wid << 10));
            gld_lds16(ga1 + off, buf + ((4 + wid) << 10));
            gld_lds16(gb0 + off, buf + 8192 + (wid << 10));
        }
        const char* buf = lds[cur];
        bf16x8 af[4], bfr[2];
#pragma unroll
        for (int m = 0; m < 4; ++m)
            af[m] = *(const bf16x8*)(buf + (((wr << 2) + m) << 10) + (l << 4));
#pragma unroll
        for (int n = 0; n < 2; ++n)
            bfr[n] = *(const bf16x8*)(buf + 8192 + (((wc << 1) + n) << 10) + (l << 4));
#pragma unroll
        for (int m = 0; m < 4; ++m)
#pragma unroll
            for (int n = 0; n < 2; ++n)
                acc[m][n] = __builtin_amdgcn_mfma_f32_16x16x32_bf16(af[m], bfr[n], acc[m][n], 0, 0, 0);
        __syncthreads();             // drains global_load_lds (vmcnt) + protects buffer reuse
        cur ^= 1;
    }

    // epilogue: C/D layout col=lane&15, row=(lane>>4)*4+reg  [m89-verified]
    int lr = l >> 4, lc = l & 15;
#pragma unroll
    for (int n = 0; n < 2; ++n) {
        int o = (blockIdx.y << 6) + (wc << 5) + (n << 4) + lc;
        float bv = bias[o];
#pragma unroll
        for (int m = 0; m < 4; ++m) {
            int r0 = (blockIdx.x << 7) + (wr << 6) + (m << 4) + (lr << 2);
#pragma unroll
            for (int j = 0; j < 4; ++j)
                out[(size_t)(r0 + j) * ON_ + o] = acc[m][n][j] + bv;
        }
    }
}

extern "C" void kernel_launch(void* const* d_in, const int* in_sizes, int n_in,
                              void* d_out, int out_size, void* d_ws, size_t ws_size,
                              hipStream_t stream) {
    const float* x      = (const float*)d_in[0];
    const float* edge_w = (const float*)d_in[1];
    const float* edge_b = (const float*)d_in[2];
    const float* comb_w = (const float*)d_in[3];
    float* out = (float*)d_out;

    char* ws = (char*)d_ws;
    char* Apk = ws;                                   // 8192*1536*2 = 25,165,824 B
    char* Bpk = ws + 25165824;                        //  1536*512*2 =  1,572,864 B
    float* bias = (float*)(ws + 25165824 + 1572864);  //  512*4 B

    hipMemsetAsync(bias, 0, ON_ * sizeof(float), stream);
    hipLaunchKernelGGL(pack_A, dim3((MB / 16) * NKS / 4), dim3(256), 0, stream, x, (uint4*)Apk);
    hipLaunchKernelGGL(pack_B, dim3((ON_ / 16) * NKS / 4), dim3(256), 0, stream, edge_w, comb_w, (uint4*)Bpk);
    hipLaunchKernelGGL(bias_k, dim3(16), dim3(256), 0, stream, comb_w, edge_b, bias);
    hipLaunchKernelGGL(gemm_k, dim3(MB / 128, ON_ / 64), dim3(256), 0, stream, Apk, Bpk, bias, out);
}

// Round 2
// 46.660 us; speedup vs baseline: 1.1516x; 1.1516x over previous
//
#include <hip/hip_runtime.h>
#include <hip/hip_bf16.h>
#include <stdint.h>

// KANLayer as GEMM: C[8192,512] = A[8192,1536]@W[1536,512] + bias, bf16 MFMA, fp32 accum.
// A[b, p*512+i] = x[b,i]^(p+1);  W[p*512+i, o] = edge_w[i,o,p]*comb_w[i,o];  bias[o] = sum_i comb_w*edge_b.

static constexpr int MB   = 8192;
static constexpr int IN_  = 512;
static constexpr int ON_  = 512;
static constexpr int KK   = 1536;
static constexpr int NKS  = KK / 32;   // 48 k-steps of 32

typedef __bf16 bf16x8 __attribute__((ext_vector_type(8)));
typedef float  f32x4  __attribute__((ext_vector_type(4)));

__device__ __forceinline__ unsigned int f2bf(float f) {
    unsigned int u = __float_as_uint(f);
    return ((u + 0x7FFFu + ((u >> 16) & 1u)) >> 16);   // RNE bf16, finite inputs
}

__device__ __forceinline__ void gld_lds16(const void* g, void* l) {
    __builtin_amdgcn_global_load_lds(
        (const __attribute__((address_space(1))) unsigned int*)(uintptr_t)g,
        (__attribute__((address_space(3))) unsigned int*)(unsigned int)(uintptr_t)l,
        16, 0, 0);
}

// ---- pack A: read x ONCE, emit x, x^2, x^3 packed fragment-major.
// Apk chunk index (rb*NKS + ks)*64 + lane, ks = p*16 + ic; lane l holds A[rb*16+(l&15)][...]
__global__ __launch_bounds__(256) void pack_A(const float* __restrict__ x, uint4* __restrict__ Apk) {
    int id = blockIdx.x * 256 + threadIdx.x;   // (rb*16 + ic)*64 + l
    int l  = id & 63;
    int t  = id >> 6;
    int ic = t & 15;
    int rb = t >> 4;
    int b  = rb * 16 + (l & 15);
    int i0 = ic * 32 + ((l >> 4) << 3);
    const float4* xp = (const float4*)(x + (size_t)b * IN_ + i0);
    float4 v0 = xp[0], v1 = xp[1];
    float f[8] = {v0.x, v0.y, v0.z, v0.w, v1.x, v1.y, v1.z, v1.w};
    unsigned int w1[4], w2[4], w3[4];
#pragma unroll
    for (int j = 0; j < 4; ++j) {
        float a = f[2 * j], c = f[2 * j + 1];
        float a2 = a * a, c2 = c * c;
        w1[j] = f2bf(a)      | (f2bf(c)      << 16);
        w2[j] = f2bf(a2)     | (f2bf(c2)     << 16);
        w3[j] = f2bf(a2 * a) | (f2bf(c2 * c) << 16);
    }
    size_t base = ((size_t)rb * NKS + ic) * 64 + l;
    Apk[base]            = make_uint4(w1[0], w1[1], w1[2], w1[3]);
    Apk[base + 16 * 64]  = make_uint4(w2[0], w2[1], w2[2], w2[3]);
    Apk[base + 32 * 64]  = make_uint4(w3[0], w3[1], w3[2], w3[3]);
}

// ---- pack B (blocks 0..383) + bias reduction (blocks 384..391), fused to save a launch + memset.
__global__ __launch_bounds__(256) void pack_B_bias(const float* __restrict__ edge_w, const float* __restrict__ comb_w,
                                                   const float* __restrict__ edge_b,
                                                   uint4* __restrict__ Bpk, float* __restrict__ bias) {
    if (blockIdx.x < 384) {
        int id   = blockIdx.x * 256 + threadIdx.x;  // ((cb*NKS)+ks)*64 + l
        int l    = id & 63;
        int cbks = id >> 6;
        int ks   = cbks % NKS;
        int cb   = cbks / NKS;
        int o    = cb * 16 + (l & 15);
        int k0   = ks * 32 + ((l >> 4) << 3);
        int p    = k0 >> 9;
        int i0   = k0 & 511;
        unsigned int w[4];
#pragma unroll
        for (int j = 0; j < 4; ++j) {
            int ia = i0 + 2 * j, ic = ia + 1;
            float va = edge_w[((size_t)ia * ON_ + o) * 3 + p] * comb_w[(size_t)ia * ON_ + o];
            float vc = edge_w[((size_t)ic * ON_ + o) * 3 + p] * comb_w[(size_t)ic * ON_ + o];
            w[j] = f2bf(va) | (f2bf(vc) << 16);
        }
        Bpk[id] = make_uint4(w[0], w[1], w[2], w[3]);
    } else {
        __shared__ float red[4][64];
        int bo = blockIdx.x - 384;          // 0..7, 64 o's each
        int tt = threadIdx.x;
        int o  = bo * 64 + (tt & 63);
        int iseg = tt >> 6;
        float s = 0.f;
        int ib = iseg * 128;
#pragma unroll 4
        for (int i = ib; i < ib + 128; ++i)
            s += comb_w[(size_t)i * ON_ + o] * edge_b[(size_t)i * ON_ + o];
        red[iseg][tt & 63] = s;
        __syncthreads();
        if (tt < 64)
            bias[bo * 64 + tt] = red[0][tt] + red[1][tt] + red[2][tt] + red[3][tt];
    }
}

// ---- GEMM: BM=128, BN=64, BK=32; 4 waves (2x2); 4-deep LDS pipeline, counted vmcnt (T3/T4).
// Per wave per k-step: 3 gld_lds (2 A chunks + 1 B chunk), 6 ds_read_b128, 8 MFMA.
#define GEMM_STEP(KS, DOWAIT, WAITSTR) do {                                                  \
    int nx_ = (KS) + 3;                                                                      \
    if (nx_ < NKS) {                                                                         \
        char* sbuf_ = lds[nx_ & 3];                                                          \
        size_t off_ = (size_t)nx_ << 10;                                                     \
        gld_lds16(ga0 + off_, sbuf_ + (wid << 10));                                          \
        gld_lds16(ga1 + off_, sbuf_ + ((4 + wid) << 10));                                    \
        gld_lds16(gb0 + off_, sbuf_ + 8192 + (wid << 10));                                   \
    }                                                                                        \
    const char* buf_ = lds[(KS) & 3];                                                        \
    bf16x8 af_[4], bf_[2];                                                                   \
    _Pragma("unroll")                                                                        \
    for (int m = 0; m < 4; ++m)                                                              \
        af_[m] = *(const bf16x8*)(buf_ + (((wr << 2) + m) << 10) + (l << 4));                \
    _Pragma("unroll")                                                                        \
    for (int n = 0; n < 2; ++n)                                                              \
        bf_[n] = *(const bf16x8*)(buf_ + 8192 + (((wc << 1) + n) << 10) + (l << 4));         \
    _Pragma("unroll")                                                                        \
    for (int m = 0; m < 4; ++m)                                                              \
        _Pragma("unroll")                                                                    \
        for (int n = 0; n < 2; ++n)                                                          \
            acc[m][n] = __builtin_amdgcn_mfma_f32_16x16x32_bf16(af_[m], bf_[n], acc[m][n], 0, 0, 0); \
    if (DOWAIT) {                                                                            \
        asm volatile("s_waitcnt " WAITSTR ::: "memory");                                     \
        __builtin_amdgcn_s_barrier();                                                        \
    }                                                                                        \
} while (0)

__global__ __launch_bounds__(256) void gemm_k(const char* __restrict__ Apk, const char* __restrict__ Bpk,
                                              const float* __restrict__ bias, float* __restrict__ out) {
    __shared__ char lds[4][12288];   // per buf: A 8KB @0, B 4KB @8192
    int tid = threadIdx.x;
    int l   = tid & 63;
    int wid = tid >> 6;
    int wr  = wid >> 1, wc = wid & 1;

    // bijective XCD swizzle: XCD c owns bx in [c*8, c*8+8) x all 8 by -> A panels L2-resident (3.1MB/XCD)
    int d  = blockIdx.x;                 // 0..511
    int w  = (d & 7) * 64 + (d >> 3);    // work id, bx-major
    int bx = w >> 3, by = w & 7;
    int rb0 = bx * 8;                    // 8 row-blocks of 16 => BM=128
    int cb0 = by * 4;                    // 4 col-blocks of 16 => BN=64

    const char* ga0 = Apk + ((size_t)(rb0 + wid)     * NKS) * 1024 + (l << 4);
    const char* ga1 = Apk + ((size_t)(rb0 + 4 + wid) * NKS) * 1024 + (l << 4);
    const char* gb0 = Bpk + ((size_t)(cb0 + wid)     * NKS) * 1024 + (l << 4);

    f32x4 acc[4][2] = {};

    // prologue: stage ks=0,1,2
#pragma unroll
    for (int t = 0; t < 3; ++t) {
        char* buf = lds[t];
        size_t off = (size_t)t << 10;
        gld_lds16(ga0 + off, buf + (wid << 10));
        gld_lds16(ga1 + off, buf + ((4 + wid) << 10));
        gld_lds16(gb0 + off, buf + 8192 + (wid << 10));
    }
    asm volatile("s_waitcnt vmcnt(6)" ::: "memory");   // ks=0's 3 loads done
    __builtin_amdgcn_s_barrier();

#pragma unroll 4
    for (int ks = 0; ks < 44; ++ks)
        GEMM_STEP(ks, 1, "vmcnt(6)");    // steady state: ks+1 done, ks+2/ks+3 in flight
    GEMM_STEP(44, 1, "vmcnt(6)");
    GEMM_STEP(45, 1, "vmcnt(3)");        // only ks=47's 3 loads may remain
    GEMM_STEP(46, 1, "vmcnt(0)");
    GEMM_STEP(47, 0, "");                // last: no wait/barrier needed

    // epilogue: C/D layout col=lane&15, row=(lane>>4)*4+reg
    int lr = l >> 4, lc = l & 15;
#pragma unroll
    for (int n = 0; n < 2; ++n) {
        int o = (by << 6) + (wc << 5) + (n << 4) + lc;
        float bv = bias[o];
#pragma unroll
        for (int m = 0; m < 4; ++m) {
            int r0 = (bx << 7) + (wr << 6) + (m << 4) + (lr << 2);
#pragma unroll
            for (int j = 0; j < 4; ++j)
                out[(size_t)(r0 + j) * ON_ + o] = acc[m][n][j] + bv;
        }
    }
}

extern "C" void kernel_launch(void* const* d_in, const int* in_sizes, int n_in,
                              void* d_out, int out_size, void* d_ws, size_t ws_size,
                              hipStream_t stream) {
    const float* x      = (const float*)d_in[0];
    const float* edge_w = (const float*)d_in[1];
    const float* edge_b = (const float*)d_in[2];
    const float* comb_w = (const float*)d_in[3];
    float* out = (float*)d_out;

    char* ws = (char*)d_ws;
    char* Apk = ws;                                   // 8192*1536*2 = 25,165,824 B
    char* Bpk = ws + 25165824;                        //  1536*512*2 =  1,572,864 B
    float* bias = (float*)(ws + 25165824 + 1572864);  //  512*4 B

    hipLaunchKernelGGL(pack_A, dim3((MB / 16) * 16 * 64 / 256), dim3(256), 0, stream, x, (uint4*)Apk);
    hipLaunchKernelGGL(pack_B_bias, dim3(384 + 8), dim3(256), 0, stream, edge_w, comb_w, edge_b, (uint4*)Bpk, bias);
    hipLaunchKernelGGL(gemm_k, dim3(512), dim3(256), 0, stream, Apk, Bpk, bias, out);
}